// Round 6
// baseline (349.123 us; speedup 1.0000x reference)
//
#include <hip/hip_runtime.h>
#include <math.h>

#define B_ 32
#define Q_ 16
#define D_ 10
#define L_ 1000
#define E_ 300
#define NCH 75          // float4 chunks per row
#define LSPLIT 8
#define ROWS 125        // valid rows per block
#define RWAVE 128       // padded row count

// ---------------------------------------------------------------------------
// Kernel 1 (prep): gate logits -> softmax -> fused per-query weight
//   wq[b,q]    = softmax(gate_logits)[b,q] * out_w * w2
//   invNq[b,q] = 1/||emb[q_tok]||
//   score[b,d] = out_w*(w2*b1 + b2) + out_b   (atomics add onto this)
// ---------------------------------------------------------------------------
__global__ __launch_bounds__(256) void drmm_prep(
    const int* __restrict__ bq, const float* __restrict__ emb,
    const float* __restrict__ gate_w, const float* __restrict__ gate_b,
    const float* __restrict__ b1, const float* __restrict__ w2,
    const float* __restrict__ b2, const float* __restrict__ out_w,
    const float* __restrict__ out_b,
    float* __restrict__ wqBuf, float* __restrict__ invNqBuf,
    float* __restrict__ score)
{
    const int b = blockIdx.x;
    const int tid = threadIdx.x;
    const int w = tid >> 6, lane = tid & 63;
    __shared__ float logits[Q_];

#pragma unroll
    for (int i = 0; i < 4; ++i) {
        const int q = w * 4 + i;
        const int tok = bq[b * Q_ + q];
        const float* row = emb + (size_t)tok * E_;
        float4 dv = *(const float4*)(row + 4 * lane);
        float4 gv = *(const float4*)(gate_w + 4 * lane);
        float pd = dv.x * gv.x + dv.y * gv.y + dv.z * gv.z + dv.w * gv.w;
        float ps = dv.x * dv.x + dv.y * dv.y + dv.z * dv.z + dv.w * dv.w;
        if (lane < 11) {
            float4 dv2 = *(const float4*)(row + 256 + 4 * lane);
            float4 gv2 = *(const float4*)(gate_w + 256 + 4 * lane);
            pd += dv2.x * gv2.x + dv2.y * gv2.y + dv2.z * gv2.z + dv2.w * gv2.w;
            ps += dv2.x * dv2.x + dv2.y * dv2.y + dv2.z * dv2.z + dv2.w * dv2.w;
        }
#pragma unroll
        for (int off = 32; off > 0; off >>= 1) {
            pd += __shfl_xor(pd, off);
            ps += __shfl_xor(ps, off);
        }
        if (lane == 0) {
            logits[q] = pd + gate_b[0];
            invNqBuf[b * Q_ + q] = 1.0f / sqrtf(ps);
        }
    }
    __syncthreads();

    if (tid == 0) {
        float m = -1e30f;
        for (int q = 0; q < Q_; ++q) m = fmaxf(m, logits[q]);
        float e[Q_];
        float s = 0.f;
        for (int q = 0; q < Q_; ++q) { e[q] = expf(logits[q] - m); s += e[q]; }
        const float sc = out_w[0] * w2[0] / s;
        for (int q = 0; q < Q_; ++q) wqBuf[b * Q_ + q] = e[q] * sc;
    }
    if (tid < D_)
        score[b * D_ + tid] = out_w[0] * (w2[0] * b1[0] + b2[0]) + out_b[0];
}

// ---------------------------------------------------------------------------
// Kernel 2 (main): K-split across waves + 2-row register blocking.
//  - block (ls,d,b) owns 125 rows; ALL 4 waves cover all rows, each wave a
//    line-aligned chunk range: [0,20) [20,40) [40,60) [60,75)
//  - lane owns rows {l, 64+l}: per chunk 2 dtile reads + 16 q broadcasts
//    amortized over 2 rows (q-broadcast count 4x lower than R5)
//  - doc gather: R5's proven quad-coalesced wave-private staging (full 64 B
//    lines), single-buffered tile + register prefetch + wave_barrier
//  - dtile slot = 4r + c + (r>>3): verified uniform 8/bank for both the
//    staging write and the row read patterns
//  - partial dots reduced across waves through a buffer aliased over qtile
//    (2 passes, 3 block barriers total), then bin+weight+one atomic
// ---------------------------------------------------------------------------
__global__ __launch_bounds__(256) void drmm_main(
    const int* __restrict__ bq, const int* __restrict__ bdocs,
    const float* __restrict__ emb, const float* __restrict__ w1,
    const float* __restrict__ wqBuf, const float* __restrict__ invNqBuf,
    float* __restrict__ score)
{
    const int ls = blockIdx.x;   // 0..7, 125 rows each
    const int d  = blockIdx.y;
    const int b  = blockIdx.z;
    const int t  = threadIdx.x;
    const int w  = t >> 6, l = t & 63;

    __shared__ float4 qtile[Q_ * NCH];   // [q*75+c] 19.2 KB (reused for reduce)
    __shared__ float4 dtile[4][528];     // per-wave, slot = 4r+c+(r>>3), 33.8 KB
    __shared__ int    toksm[RWAVE];

    // ---- stage tokens + qtile
    if (t < RWAVE) {
        const int r = (t < ROWS) ? t : (ROWS - 1);
        toksm[t] = bdocs[(b * D_ + d) * L_ + ls * ROWS + r];
    }
    {
        const int q = t >> 4, c0 = t & 15;
        const float* qr = emb + (size_t)bq[b * Q_ + q] * E_;
#pragma unroll
        for (int k = 0; k < 5; ++k) {
            const int c = c0 + 16 * k;
            if (c < NCH) qtile[q * NCH + c] = *(const float4*)(qr + 4 * c);
        }
    }
    __syncthreads();

    // wave chunk range (line-aligned groups of 4)
    const int cbeg = 20 * w;
    const int cend = (w == 3) ? NCH : (cbeg + 20);
    const int ngr  = (cend - cbeg + 3) >> 2;        // 5,5,5,4

    // staging bases: lane l stages chunk cbase+(l&3) of rows (l>>2)+16m
    const float* sbase[8];
#pragma unroll
    for (int m = 0; m < 8; ++m)
        sbase[m] = emb + (size_t)toksm[(l >> 2) + 16 * m] * E_;
    const int csub = l & 3;

    float4* const myt = &dtile[w][0];
    const int wbase = 4 * (l >> 2) + (l & 3) + (l >> 5);  // +66 per m
    const int r0 = 4 * l + (l >> 3);                      // row l, +c
    const int r1 = r0 + 264;                              // row 64+l, +c

    float acc0[Q_], acc1[Q_];
#pragma unroll
    for (int q = 0; q < Q_; ++q) { acc0[q] = 0.f; acc1[q] = 0.f; }
    float sq0 = 0.f, sq1 = 0.f;

    float4 st[8];
    {
        const int n = (cend - cbeg < 4) ? (cend - cbeg) : 4;
        const int ch = cbeg + ((csub < n) ? csub : (n - 1));
#pragma unroll
        for (int m = 0; m < 8; ++m) st[m] = *(const float4*)(sbase[m] + 4 * ch);
    }

#pragma unroll 1
    for (int g = 0; g < ngr; ++g) {
        const int c0 = cbeg + 4 * g;
        const int n  = (cend - c0 < 4) ? (cend - c0) : 4;
        // stage group g (uniform 8/bank writes)
#pragma unroll
        for (int m = 0; m < 8; ++m) myt[wbase + 66 * m] = st[m];
        // prefetch group g+1 (spans this group's compute)
        if (g + 1 < ngr) {
            const int c0n = c0 + 4;
            const int nn  = (cend - c0n < 4) ? (cend - c0n) : 4;
            const int ch  = c0n + ((csub < nn) ? csub : (nn - 1));
#pragma unroll
            for (int m = 0; m < 8; ++m)
                st[m] = *(const float4*)(sbase[m] + 4 * ch);
        }
        __builtin_amdgcn_wave_barrier();   // order writes before reads (HW DS in-order)
        // compute: 2 rows per lane, q broadcasts amortized over both
#pragma unroll
        for (int c = 0; c < 4; ++c) {
            if (c < n) {                               // wave-uniform
                const int chunk = c0 + c;
                const float4 dv0 = myt[r0 + c];
                const float4 dv1 = myt[r1 + c];
                sq0 = fmaf(dv0.x, dv0.x, fmaf(dv0.y, dv0.y,
                      fmaf(dv0.z, dv0.z, fmaf(dv0.w, dv0.w, sq0))));
                sq1 = fmaf(dv1.x, dv1.x, fmaf(dv1.y, dv1.y,
                      fmaf(dv1.z, dv1.z, fmaf(dv1.w, dv1.w, sq1))));
#pragma unroll
                for (int q = 0; q < Q_; ++q) {
                    const float4 qv = qtile[q * NCH + chunk];   // broadcast
                    acc0[q] = fmaf(dv0.w, qv.w, fmaf(dv0.z, qv.z,
                              fmaf(dv0.y, qv.y, fmaf(dv0.x, qv.x, acc0[q]))));
                    acc1[q] = fmaf(dv1.w, qv.w, fmaf(dv1.z, qv.z,
                              fmaf(dv1.y, qv.y, fmaf(dv1.x, qv.x, acc1[q]))));
                }
            }
        }
        __builtin_amdgcn_wave_barrier();   // reads of g before writes of g+1
    }

    // ---- cross-wave reduction (buffer aliased over qtile), bin, accumulate
    __syncthreads();                       // all compute done; qtile reusable
    float* red = (float*)qtile;            // 256 threads x 17 floats = 17.4 KB
    float blockTotal = 0.f;                // meaningful in thread 0 only

    // ---- pass 0: rows l (0..63)
    {
        float* p = red + t * 17;
#pragma unroll
        for (int q = 0; q < Q_; ++q) p[q] = acc0[q];
        p[16] = sq0;
    }
    __syncthreads();
    if (w == 0) {
        float dot[Q_]; float sqv = 0.f;
#pragma unroll
        for (int q = 0; q < Q_; ++q) dot[q] = 0.f;
#pragma unroll
        for (int ww = 0; ww < 4; ++ww) {
            const float* p = red + (ww * 64 + l) * 17;
#pragma unroll
            for (int q = 0; q < Q_; ++q) dot[q] += p[q];
            sqv += p[16];
        }
        float tot = 0.f;
        {
            const float nd = sqrtf(sqv);
            const float w10 = w1[0], w11 = w1[1], w12 = w1[2],
                        w13 = w1[3], w14 = w1[4];
#pragma unroll
            for (int q = 0; q < Q_; ++q) {
                const float a = dot[q] * invNqBuf[b * Q_ + q];
                const float wv = (a < -nd)        ? 0.f
                               : (a < -0.5f * nd) ? w10
                               : (a < 0.f)        ? w11
                               : (a < 0.5f * nd)  ? w12
                               : (a < nd)         ? w13
                               : (a <= nd)        ? w14
                                                  : 0.f;
                tot = fmaf(wqBuf[b * Q_ + q], wv, tot);
            }
        }
#pragma unroll
        for (int off = 32; off > 0; off >>= 1) tot += __shfl_xor(tot, off);
        if (l == 0) blockTotal += tot;
    }
    __syncthreads();

    // ---- pass 1: rows 64+l (valid while 64+l < 125)
    {
        float* p = red + t * 17;
#pragma unroll
        for (int q = 0; q < Q_; ++q) p[q] = acc1[q];
        p[16] = sq1;
    }
    __syncthreads();
    if (w == 0) {
        float dot[Q_]; float sqv = 0.f;
#pragma unroll
        for (int q = 0; q < Q_; ++q) dot[q] = 0.f;
#pragma unroll
        for (int ww = 0; ww < 4; ++ww) {
            const float* p = red + (ww * 64 + l) * 17;
#pragma unroll
            for (int q = 0; q < Q_; ++q) dot[q] += p[q];
            sqv += p[16];
        }
        float tot = 0.f;
        if (64 + l < ROWS) {
            const float nd = sqrtf(sqv);
            const float w10 = w1[0], w11 = w1[1], w12 = w1[2],
                        w13 = w1[3], w14 = w1[4];
#pragma unroll
            for (int q = 0; q < Q_; ++q) {
                const float a = dot[q] * invNqBuf[b * Q_ + q];
                const float wv = (a < -nd)        ? 0.f
                               : (a < -0.5f * nd) ? w10
                               : (a < 0.f)        ? w11
                               : (a < 0.5f * nd)  ? w12
                               : (a < nd)         ? w13
                               : (a <= nd)        ? w14
                                                  : 0.f;
                tot = fmaf(wqBuf[b * Q_ + q], wv, tot);
            }
        }
#pragma unroll
        for (int off = 32; off > 0; off >>= 1) tot += __shfl_xor(tot, off);
        if (l == 0) blockTotal += tot;
    }

    if (t == 0) atomicAdd(&score[b * D_ + d], blockTotal);
}

extern "C" void kernel_launch(void* const* d_in, const int* in_sizes, int n_in,
                              void* d_out, int out_size, void* d_ws, size_t ws_size,
                              hipStream_t stream)
{
    const int*   bq     = (const int*)d_in[0];
    const int*   bdocs  = (const int*)d_in[1];
    const float* emb    = (const float*)d_in[2];
    const float* gate_w = (const float*)d_in[3];
    const float* gate_b = (const float*)d_in[4];
    const float* w1     = (const float*)d_in[5];
    const float* b1     = (const float*)d_in[6];
    const float* w2     = (const float*)d_in[7];
    const float* b2     = (const float*)d_in[8];
    const float* out_w  = (const float*)d_in[9];
    const float* out_b  = (const float*)d_in[10];

    float* score  = (float*)d_out;
    float* wqBuf  = (float*)d_ws;          // 512 floats
    float* invNq  = wqBuf + B_ * Q_;       // 512 floats  (ws usage: 4 KiB)

    drmm_prep<<<dim3(B_), dim3(256), 0, stream>>>(
        bq, emb, gate_w, gate_b, b1, w2, b2, out_w, out_b, wqBuf, invNq, score);

    drmm_main<<<dim3(LSPLIT, D_, B_), dim3(256), 0, stream>>>(
        bq, bdocs, emb, w1, wqBuf, invNq, score);
}